// Round 1
// baseline (6618.800 us; speedup 1.0000x reference)
//
#include <hip/hip_runtime.h>
#include <stdint.h>

typedef _Float16 h2 __attribute__((ext_vector_type(2)));
typedef float    f4 __attribute__((ext_vector_type(4)));

#if __has_builtin(__builtin_amdgcn_fdot2)
__device__ __forceinline__ float dot2(uint32_t a, uint32_t b, float c) {
    return __builtin_amdgcn_fdot2(__builtin_bit_cast(h2, a),
                                  __builtin_bit_cast(h2, b), c, false);
}
#else
__device__ __forceinline__ float dot2(uint32_t a, uint32_t b, float c) {
    h2 ha = __builtin_bit_cast(h2, a), hb = __builtin_bit_cast(h2, b);
    return c + (float)ha[0]*(float)hb[0] + (float)ha[1]*(float)hb[1];
}
#endif

#define TT 4096
#define NB 32
#define HD 512
#define JL 16              // k-pairs per col held in per-thread LDS stash
#define JTOT 64            // k-pairs per col total (128 k rows / 2)
#define JR (JTOT - JL)     // k-pairs per col held in registers (48)
#define WSTRIDE 65         // uints per thread in LDS stash (64 data + 1 pad -> bank-conflict-free)

// One block per batch row. 512 threads: kg = tid>>7 (k-slice of 128 rows),
// colg = tid&127 (4 output columns). W_int resident as fp16 half2 k-pairs:
// 16 pairs/col in LDS stash, 48 pairs/col in VGPRs (fully unrolled).
__global__ __launch_bounds__(512, 2)
void esn_kernel(const float* __restrict__ X, const float* __restrict__ W_in,
                const float* __restrict__ W_int, const float* __restrict__ noise,
                float* __restrict__ out)
{
    __shared__ _Float16 s_buf[2][HD];          // 2 KB  (recurrent state, fp16)
    __shared__ float    pads[4][HD];           // 8 KB  (per-kg partial sums)
    __shared__ uint32_t wstash[512 * WSTRIDE]; // 133 KB (LDS part of W, half2-packed)

    const int tid  = threadIdx.x;
    const int b    = blockIdx.x;
    const int kg   = tid >> 7;      // 0..3
    const int colg = tid & 127;     // 0..127
    const int c0   = colg * 4;      // first of this thread's 4 columns

    // Input weights for the reduce phase (col = tid), kept in registers.
    const float win0 = W_in[tid*3 + 0];
    const float win1 = W_in[tid*3 + 1];
    const float win2 = W_in[tid*3 + 2];

    // ---- Prologue: load + pack W_int (fp32 -> half2 k-pairs) ----
    uint32_t wreg[4][JR];
    {
        const f4* Wv = (const f4*)W_int;   // W_int[k][h], 4 cols at a time
        // LDS-resident part (dynamic j is fine; destination is LDS)
        for (int j = 0; j < JL; ++j) {
            const int k = kg*128 + 2*j;
            f4 r0 = Wv[(size_t)k*128 + colg];
            f4 r1 = Wv[(size_t)(k+1)*128 + colg];
            #pragma unroll
            for (int c = 0; c < 4; ++c) {
                h2 w; w[0] = (_Float16)r0[c]; w[1] = (_Float16)r1[c];
                wstash[tid*WSTRIDE + j*4 + c] = __builtin_bit_cast(uint32_t, w);
            }
        }
        // Register-resident part (MUST fully unroll -> static wreg indices)
        #pragma unroll
        for (int j = 0; j < JR; ++j) {
            const int k = kg*128 + 2*(JL + j);
            f4 r0 = Wv[(size_t)k*128 + colg];
            f4 r1 = Wv[(size_t)(k+1)*128 + colg];
            #pragma unroll
            for (int c = 0; c < 4; ++c) {
                h2 w; w[0] = (_Float16)r0[c]; w[1] = (_Float16)r1[c];
                wreg[c][j] = __builtin_bit_cast(uint32_t, w);
            }
        }
    }
    s_buf[0][tid] = (_Float16)0.01f;   // prev0 = 0.01
    __syncthreads();

    const float* Xb   = X   + (size_t)b * TT * 3;
    float*       outb = out + (size_t)b * TT * HD;
    const size_t nb   = (size_t)b * HD + tid;

    int cur = 0;
    for (int t = 0; t < TT; ++t) {
        // Prefetch this step's noise + raw input early; consumed after k-loop.
        const float nz = noise[(size_t)t*(NB*HD) + nb];
        const float x0 = Xb[t*3 + 0];
        const float x1 = Xb[t*3 + 1];
        const float x2 = Xb[t*3 + 2];

        // ---- Phase A: partial dot-products over this thread's k-slice ----
        const uint32_t* s32 = (const uint32_t*)(&s_buf[cur][0]); // half2 pairs
        const int sb = kg*64;
        float a0 = 0.f, a1 = 0.f, a2 = 0.f, a3 = 0.f;

        #pragma unroll
        for (int j = 0; j < JL; ++j) {
            const uint32_t sv = s32[sb + j];          // wave-uniform broadcast
            const int wb = tid*WSTRIDE + j*4;
            a0 = dot2(sv, wstash[wb+0], a0);
            a1 = dot2(sv, wstash[wb+1], a1);
            a2 = dot2(sv, wstash[wb+2], a2);
            a3 = dot2(sv, wstash[wb+3], a3);
        }
        #pragma unroll
        for (int j = 0; j < JR; ++j) {
            const uint32_t sv = s32[sb + JL + j];
            a0 = dot2(sv, wreg[0][j], a0);
            a1 = dot2(sv, wreg[1][j], a1);
            a2 = dot2(sv, wreg[2][j], a2);
            a3 = dot2(sv, wreg[3][j], a3);
        }
        f4 pv; pv[0] = a0; pv[1] = a1; pv[2] = a2; pv[3] = a3;
        *(f4*)&pads[kg][c0] = pv;        // 16B aligned, conflict-free
        __syncthreads();

        // ---- Phase B: reduce 4 k-slices, add input+noise, tanh, emit ----
        float z = pads[0][tid] + pads[1][tid] + pads[2][tid] + pads[3][tid];
        z += win0*x0 + win1*x1 + win2*x2 + 0.01f*nz;
        const float s = tanhf(z);
        outb[(size_t)t*HD + tid] = s;
        s_buf[cur^1][tid] = (_Float16)s;
        __syncthreads();
        cur ^= 1;
    }
}

extern "C" void kernel_launch(void* const* d_in, const int* in_sizes, int n_in,
                              void* d_out, int out_size, void* d_ws, size_t ws_size,
                              hipStream_t stream)
{
    const float* X     = (const float*)d_in[0];
    const float* W_in  = (const float*)d_in[1];
    const float* W_int = (const float*)d_in[2];
    const float* noise = (const float*)d_in[3];
    float* out = (float*)d_out;

    esn_kernel<<<dim3(NB), dim3(512), 0, stream>>>(X, W_in, W_int, noise, out);
}

// Round 2
// 5375.497 us; speedup vs baseline: 1.2313x; 1.2313x over previous
//
#include <hip/hip_runtime.h>
#include <stdint.h>

typedef _Float16 h2 __attribute__((ext_vector_type(2)));
typedef float    f4 __attribute__((ext_vector_type(4)));
typedef uint32_t u4 __attribute__((ext_vector_type(4)));

#if __has_builtin(__builtin_amdgcn_fdot2)
__device__ __forceinline__ float dot2(uint32_t a, uint32_t b, float c) {
    return __builtin_amdgcn_fdot2(__builtin_bit_cast(h2, a),
                                  __builtin_bit_cast(h2, b), c, false);
}
#else
__device__ __forceinline__ float dot2(uint32_t a, uint32_t b, float c) {
    h2 ha = __builtin_bit_cast(h2, a), hb = __builtin_bit_cast(h2, b);
    return c + (float)ha[0]*(float)hb[0] + (float)ha[1]*(float)hb[1];
}
#endif

// tanh(z) = 1 - 2/(exp(2z)+1); v_exp_f32 + v_rcp path, ~1e-6 abs err.
__device__ __forceinline__ float fast_tanh(float z) {
    float e = __expf(2.0f * z);
    return 1.0f - 2.0f * __builtin_amdgcn_rcpf(e + 1.0f);
}

#define TT 4096
#define NB 32
#define HD 512
#define JL 12              // k-pairs per col in LDS  (12*4 uints/thread = 98 KB total)
#define JTOT 64            // k-pairs per col total (128 k rows / 2)
#define JR (JTOT - JL)     // k-pairs per col in registers (52 -> 208 VGPRs of W)

// One block per batch row. 512 threads: kg = tid>>7 (k-slice of 128 rows),
// colg = tid&127 (4 output columns). W_int resident as fp16 half2 k-pairs.
// waves_per_eu(2,2): pin 2 waves/SIMD so the allocator has 256 arch VGPRs
// and keeps all 208 W words in VGPRs (round 1 showed a 128-VGPR + AGPR split
// costing ~770 cyc/SIMD/step of v_accvgpr moves).
__global__ __attribute__((amdgpu_waves_per_eu(2, 2))) __launch_bounds__(512)
void esn_kernel(const float* __restrict__ X, const float* __restrict__ W_in,
                const float* __restrict__ W_int, const float* __restrict__ noise,
                float* __restrict__ out)
{
    __shared__ __align__(16) _Float16 s_buf[2][HD];  // 2 KB (state, fp16, dbuf)
    __shared__ float pads[4][HD];                    // 8 KB (per-kg partials)
    __shared__ u4 wstash[8 * JL * 64];               // 98 KB: [wave][j][lane] quads

    const int tid  = threadIdx.x;
    const int b    = blockIdx.x;
    const int w    = tid >> 6;      // wave 0..7
    const int l    = tid & 63;      // lane 0..63
    const int kg   = tid >> 7;      // 0..3   (k-slice of 128 state rows)
    const int colg = tid & 127;     // 0..127
    const int c0   = colg * 4;      // first of this thread's 4 columns

    // Input weights for the reduce phase (col = tid).
    const float win0 = W_in[tid*3 + 0];
    const float win1 = W_in[tid*3 + 1];
    const float win2 = W_in[tid*3 + 2];

    // ---- Prologue: load + pack W_int (fp32 -> half2 k-pairs) ----
    uint32_t wreg[4][JR];
    {
        const f4* Wv = (const f4*)W_int;   // W_int[k][h], 4 cols at a time
        // LDS-resident part: k-pairs 0..JL-1. Layout [wave][j][lane] so the
        // per-step wave read of quad j is 64 contiguous 16B lanes (canonical
        // conflict-free ds_read_b128 pattern).
        for (int j = 0; j < JL; ++j) {
            const int k = kg*128 + 2*j;
            f4 r0 = Wv[(size_t)k*128 + colg];
            f4 r1 = Wv[(size_t)(k+1)*128 + colg];
            u4 q;
            #pragma unroll
            for (int c = 0; c < 4; ++c) {
                h2 hw; hw[0] = (_Float16)r0[c]; hw[1] = (_Float16)r1[c];
                q[c] = __builtin_bit_cast(uint32_t, hw);
            }
            wstash[(w*JL + j)*64 + l] = q;
        }
        // Register-resident part: k-pairs JL..63 (MUST fully unroll).
        #pragma unroll
        for (int j = 0; j < JR; ++j) {
            const int k = kg*128 + 2*(JL + j);
            f4 r0 = Wv[(size_t)k*128 + colg];
            f4 r1 = Wv[(size_t)(k+1)*128 + colg];
            #pragma unroll
            for (int c = 0; c < 4; ++c) {
                h2 hw; hw[0] = (_Float16)r0[c]; hw[1] = (_Float16)r1[c];
                wreg[c][j] = __builtin_bit_cast(uint32_t, hw);
            }
        }
    }
    s_buf[0][tid] = (_Float16)0.01f;   // prev0 = 0.01
    __syncthreads();

    const float* Xb   = X   + (size_t)b * TT * 3;
    float*       outb = out + (size_t)b * TT * HD;
    const size_t nb   = (size_t)b * HD + tid;

    int cur = 0;
    for (int t = 0; t < TT; ++t) {
        // Prefetch this step's noise + raw input early; consumed after k-loop.
        const float nz = noise[(size_t)t*(NB*HD) + nb];
        const float x0 = Xb[t*3 + 0];
        const float x1 = Xb[t*3 + 1];
        const float x2 = Xb[t*3 + 2];

        // ---- Phase A: partial dot-products over this thread's k-slice ----
        // State as b128 broadcast quads, loaded on demand (short live range).
        const u4* sv4 = (const u4*)((const uint32_t*)(&s_buf[cur][0]) + kg*64);
        float a0 = 0.f, a1 = 0.f, a2 = 0.f, a3 = 0.f;
        u4 sq;

        // LDS-resident W: 12 x ds_read_b128, conflict-free contiguous layout.
        #pragma unroll
        for (int j = 0; j < JL; ++j) {
            if ((j & 3) == 0) sq = sv4[j >> 2];
            const uint32_t sv = sq[j & 3];
            u4 q = wstash[(w*JL + j)*64 + l];
            a0 = dot2(sv, q[0], a0);
            a1 = dot2(sv, q[1], a1);
            a2 = dot2(sv, q[2], a2);
            a3 = dot2(sv, q[3], a3);
        }
        // Register-resident W: pure VALU.
        #pragma unroll
        for (int j = 0; j < JR; ++j) {
            const int jg = JL + j;               // 12..63, starts quad-aligned
            if ((jg & 3) == 0) sq = sv4[jg >> 2];
            const uint32_t sv = sq[jg & 3];
            a0 = dot2(sv, wreg[0][j], a0);
            a1 = dot2(sv, wreg[1][j], a1);
            a2 = dot2(sv, wreg[2][j], a2);
            a3 = dot2(sv, wreg[3][j], a3);
        }
        f4 pv; pv[0] = a0; pv[1] = a1; pv[2] = a2; pv[3] = a3;
        *(f4*)&pads[kg][c0] = pv;        // 16B aligned, conflict-free
        __syncthreads();

        // ---- Phase B: reduce 4 k-slices, add input+noise, tanh, emit ----
        float z = pads[0][tid] + pads[1][tid] + pads[2][tid] + pads[3][tid];
        z += win0*x0 + win1*x1 + win2*x2 + 0.01f*nz;
        const float s = fast_tanh(z);
        outb[(size_t)t*HD + tid] = s;
        s_buf[cur^1][tid] = (_Float16)s;
        __syncthreads();
        cur ^= 1;
    }
}

extern "C" void kernel_launch(void* const* d_in, const int* in_sizes, int n_in,
                              void* d_out, int out_size, void* d_ws, size_t ws_size,
                              hipStream_t stream)
{
    const float* X     = (const float*)d_in[0];
    const float* W_in  = (const float*)d_in[1];
    const float* W_int = (const float*)d_in[2];
    const float* noise = (const float*)d_in[3];
    float* out = (float*)d_out;

    esn_kernel<<<dim3(NB), dim3(512), 0, stream>>>(X, W_in, W_int, noise, out);
}